// Round 1
// 67.146 us; speedup vs baseline: 1.0004x; 1.0004x over previous
//
#include <hip/hip_runtime.h>

// Problem constants (from reference):
//   N=64, C=4, LPC=8, KPL=4, D=4096, BLOCK=128, P=384
// out[n,c,d] = sum_g amp[n,c,g] * exp(-0.5*(x[n,c,d]-mu[n,c,g])^2 / sigma[n,c,g]^2)
//
// Formulation: exp(-0.5 (x-m)^2 / s^2) = exp2(-(x*r + mmr)^2),
//   r = sqrt(0.5*log2(e))/s, mmr = -m*r.
//
// This version uses packed FP32 (v_pk_fma_f32 / v_pk_mul_f32, VOP3P) by doing
// the element math on <2 x float> ext-vectors: per 2 elements per gaussian the
// cost is 1 pk_fma + 1 pk_mul + 2 v_exp + 1 pk_fma  (1.5 VALU + 1 trans per
// element, vs 3 + 1 scalar). v_exp's negate folds into the source modifier.
// Per-gaussian params are packed {r, mmr, a, 0} so the LDS broadcast is one
// ds_read_b128 per gaussian (32 reads/wave) instead of 96 ds_read_b32.

#define NN   64
#define CC   4
#define GG   32        // LPC*KPL gaussians per (n,c)
#define DD   4096
#define PP   384       // network_outputs row length
#define TPB  256       // threads per block
#define EPT  4         // one float4 per thread
// Each block covers TPB*EPT = 1024 contiguous d's of one (n,c) row.
// Grid = (DD/1024, NN*CC) = (4, 256) = 1024 blocks -> 4 blocks/CU, 4 waves/SIMD.

typedef float f32x2 __attribute__((ext_vector_type(2)));

__global__ __launch_bounds__(TPB) void gauss_mix_kernel(
    const float* __restrict__ x,
    const float* __restrict__ net,        // (N, P)
    const int*   __restrict__ amp_idx,    // (C, LPC, KPL) flat = C*32
    const int*   __restrict__ mu_idx,
    const int*   __restrict__ sigma_idx,
    float* __restrict__ out)
{
    __shared__ float4 s_p[GG];   // {r, mmr, a, pad} per gaussian

    const int row = blockIdx.y;          // n*C + c
    const int n   = row >> 2;            // / CC
    const int c   = row & (CC - 1);
    const int tid = threadIdx.x;

    if (tid < GG) {
        const int gi   = c * GG + tid;
        const int base = n * PP;
        const float a  = net[base + amp_idx[gi]];
        const float m  = net[base + mu_idx[gi]];
        const float s  = net[base + sigma_idx[gi]];
        const float r  = 0.84932178f / s;   // sqrt(0.5 * log2(e))
        s_p[tid] = make_float4(r, -m * r, a, 0.f);
    }
    __syncthreads();

    const int d0 = blockIdx.x * (TPB * EPT) + tid * EPT;
    const size_t off = (size_t)row * DD + d0;

    const float4 xv = *(const float4*)(x + off);
    f32x2 x01 = { xv.x, xv.y };
    f32x2 x23 = { xv.z, xv.w };
    f32x2 acc01 = { 0.f, 0.f };
    f32x2 acc23 = { 0.f, 0.f };

    #pragma unroll
    for (int g = 0; g < GG; ++g) {
        const float4 p = s_p[g];          // broadcast ds_read_b128, conflict-free
        const f32x2 r2   = { p.x, p.x };
        const f32x2 mmr2 = { p.y, p.y };
        const f32x2 a2   = { p.z, p.z };

        const f32x2 u01 = __builtin_elementwise_fma(x01, r2, mmr2);  // v_pk_fma_f32
        const f32x2 u23 = __builtin_elementwise_fma(x23, r2, mmr2);
        const f32x2 w01 = u01 * u01;                                 // v_pk_mul_f32
        const f32x2 w23 = u23 * u23;

        f32x2 e01, e23;
        e01.x = __builtin_amdgcn_exp2f(-w01.x);   // v_exp_f32 with neg src-mod
        e01.y = __builtin_amdgcn_exp2f(-w01.y);
        e23.x = __builtin_amdgcn_exp2f(-w23.x);
        e23.y = __builtin_amdgcn_exp2f(-w23.y);

        acc01 = __builtin_elementwise_fma(a2, e01, acc01);           // v_pk_fma_f32
        acc23 = __builtin_elementwise_fma(a2, e23, acc23);
    }

    *(float4*)(out + off) = make_float4(acc01.x, acc01.y, acc23.x, acc23.y);
}

extern "C" void kernel_launch(void* const* d_in, const int* in_sizes, int n_in,
                              void* d_out, int out_size, void* d_ws, size_t ws_size,
                              hipStream_t stream)
{
    const float* x       = (const float*)d_in[0];   // (N, C, D)
    const float* net     = (const float*)d_in[1];   // (N, P)
    const int*   amp_idx = (const int*)d_in[2];     // (C, LPC, KPL)
    const int*   mu_idx  = (const int*)d_in[3];
    const int*   sig_idx = (const int*)d_in[4];
    float*       out     = (float*)d_out;           // (N, C, D)

    dim3 grid(DD / (TPB * EPT), NN * CC);
    dim3 block(TPB);
    gauss_mix_kernel<<<grid, block, 0, stream>>>(x, net, amp_idx, mu_idx, sig_idx, out);
}